// Round 1
// baseline (899.303 us; speedup 1.0000x reference)
//
#include <hip/hip_runtime.h>
#include <hip/hip_bf16.h>

#define DIM 256
#define KNB 32
#define NSITES 20000   // B*N = 4*5000
#define LDA 264        // padded row (bf16 elems): 528 B = 33*16, conflict-free-min access

typedef __attribute__((ext_vector_type(8))) __bf16 bf16x8;
typedef __attribute__((ext_vector_type(4))) float floatx4;
typedef __attribute__((ext_vector_type(4))) unsigned short ushortx4;

union F8 { bf16x8 v; unsigned short u[8]; };

// fp32 -> bf16 round-to-nearest-even (inputs finite)
__device__ __forceinline__ unsigned short f2bf(float x) {
    unsigned u = __builtin_bit_cast(unsigned, x);
    u += 0x7fffu + ((u >> 16) & 1u);
    return (unsigned short)(u >> 16);
}

// ---------------------------------------------------------------------------
// Kernel 1: V3[s,o] = sum_d fi[s,d]*(W1-W2)[o,d] + b1[o] + b2[o]  -> v3out
// (unchanged structure; ~5-10 us, not the bottleneck)
// ---------------------------------------------------------------------------
__global__ __launch_bounds__(256, 2) void v3_kernel(
    const float* __restrict__ fi, const float* __restrict__ w1,
    const float* __restrict__ b1, const float* __restrict__ w2,
    const float* __restrict__ b2, float* __restrict__ v3out)
{
    const int tid  = threadIdx.x;
    const int w    = tid >> 6, lane = tid & 63;
    const int col  = lane & 15, quad = lane >> 4;
    const int sbase = blockIdx.x * 64;

    F8 w3f[4][8];
    float bias[4];
#pragma unroll
    for (int ot = 0; ot < 4; ++ot) {
        const int o = (4 * w + ot) * 16 + col;
        bias[ot] = b1[o] + b2[o];
        const float* p1 = w1 + o * DIM;
        const float* p2 = w2 + o * DIM;
#pragma unroll
        for (int c = 0; c < 8; ++c) {
            const int d0 = c * 32 + quad * 8;
            floatx4 a0 = *(const floatx4*)(p1 + d0);
            floatx4 a1 = *(const floatx4*)(p1 + d0 + 4);
            floatx4 s0 = *(const floatx4*)(p2 + d0);
            floatx4 s1 = *(const floatx4*)(p2 + d0 + 4);
#pragma unroll
            for (int j = 0; j < 4; ++j) {
                w3f[ot][c].u[j]     = f2bf(a0[j] - s0[j]);
                w3f[ot][c].u[j + 4] = f2bf(a1[j] - s1[j]);
            }
        }
    }

#pragma unroll 1
    for (int mt = 0; mt < 4; ++mt) {
        const int srow = sbase + mt * 16;
        if (srow >= NSITES) break;           // 20000 = 16*1250, tiles always full
        F8 a[8];
        const float* pa = fi + (size_t)(srow + col) * DIM;
#pragma unroll
        for (int c = 0; c < 8; ++c) {
            const int d0 = c * 32 + quad * 8;
            floatx4 f0 = *(const floatx4*)(pa + d0);
            floatx4 f1 = *(const floatx4*)(pa + d0 + 4);
#pragma unroll
            for (int j = 0; j < 4; ++j) {
                a[c].u[j]     = f2bf(f0[j]);
                a[c].u[j + 4] = f2bf(f1[j]);
            }
        }
#pragma unroll
        for (int ot = 0; ot < 4; ++ot) {
            floatx4 acc = {0.f, 0.f, 0.f, 0.f};
#pragma unroll
            for (int c = 0; c < 8; ++c)
                acc = __builtin_amdgcn_mfma_f32_16x16x32_bf16(a[c].v, w3f[ot][c].v, acc, 0, 0, 0);
            const int o = (4 * w + ot) * 16 + col;
#pragma unroll
            for (int r = 0; r < 4; ++r) {
                const int site = srow + quad * 4 + r;   // C/D: row = quad*4 + reg
                v3out[(size_t)site * DIM + o] = acc[r] + bias[ot];
            }
        }
    }
}

// ---------------------------------------------------------------------------
// Kernel 2 (restructured): per site s: Y[k,o] = sum_d fj[s,d,k]*W2[o,d];
//           out[s,o] = relu(max_k Y[k,o] + V3[s,o])
// NEW: 256-thr / 4-wave blocks, wave owns a 64-wide o-tile (w2f[4][8]),
// grid = 512 -> 2 independent blocks (site-streams) per CU. Doubles HBM MLP,
// decouples the per-site barrier, halves LDS a-frag reads (reuse 4 vs 2).
// ---------------------------------------------------------------------------
__global__ __launch_bounds__(256, 2) void edge_kernel(
    const float* __restrict__ fj, const float* __restrict__ w2,
    const float* __restrict__ v3buf, float* __restrict__ out)
{
    __shared__ unsigned short As[2][KNB * LDA];   // 2 * 16.5 KB = 33 KB/block

    const int tid  = threadIdx.x;
    const int w    = tid >> 6, lane = tid & 63;
    const int col  = lane & 15, quad = lane >> 4;
    // staging: thread covers d in [db,db+8), k in [4kg,4kg+4)
    const int kg = tid & 7, dg = tid >> 3;        // dg 0..31
    const int db = dg * 8;

    // W2 B-fragments: wave w covers o in [64w, 64w+64): w2f[ot][c] = W2[o][d0..d0+7]
    F8 w2f[4][8];
#pragma unroll
    for (int ot = 0; ot < 4; ++ot) {
        const int o = 64 * w + ot * 16 + col;
        const float* p = w2 + o * DIM;
#pragma unroll
        for (int c = 0; c < 8; ++c) {
            const int d0 = c * 32 + quad * 8;
            floatx4 f0 = *(const floatx4*)(p + d0);
            floatx4 f1 = *(const floatx4*)(p + d0 + 4);
#pragma unroll
            for (int j = 0; j < 4; ++j) {
                w2f[ot][c].u[j]     = f2bf(f0[j]);
                w2f[ot][c].u[j + 4] = f2bf(f1[j]);
            }
        }
    }

    const int G = gridDim.x;
    floatx4 r[8];
    auto load_r = [&](int ss) {
        const float* p = fj + (size_t)ss * (DIM * KNB) + (db * KNB + kg * 4);
#pragma unroll
        for (int j = 0; j < 8; ++j)
            r[j] = *(const floatx4*)(p + j * KNB);   // 8x 128B segments/wave, coalesced
    };

    int s = blockIdx.x;
    load_r(s);
    int buf = 0;
    for (;;) {
        // cvt + transposed LDS write: As[k][d] = bf16(fj[s][d][k]); b128 writes,
        // bank-start (4kg+4dg)%32 -> structural-minimum, no conflicts
#pragma unroll
        for (int kk = 0; kk < 4; ++kk) {
            F8 v;
#pragma unroll
            for (int j = 0; j < 8; ++j) v.u[j] = f2bf(r[j][kk]);
            *(bf16x8*)&As[buf][(4 * kg + kk) * LDA + db] = v.v;
        }
        __syncthreads();   // one barrier per site

        const int sn = s + G;
        if (sn < NSITES) load_r(sn);                 // prefetch overlaps MFMA phase

        const int oidx = s * DIM + 64 * w + lane;    // wave stores 256B contiguous
        const float v3 = v3buf[oidx];

        floatx4 acc[2][4];
#pragma unroll
        for (int mt = 0; mt < 2; ++mt)
#pragma unroll
            for (int ot = 0; ot < 4; ++ot) acc[mt][ot] = (floatx4){0.f, 0.f, 0.f, 0.f};

#pragma unroll
        for (int mt = 0; mt < 2; ++mt) {
            const unsigned short* arow = &As[buf][(mt * 16 + col) * LDA + quad * 8];
#pragma unroll
            for (int ch = 0; ch < 2; ++ch) {         // split a[] to cap VGPR peak
                bf16x8 a0 = *(const bf16x8*)(arow + (ch * 4 + 0) * 32);
                bf16x8 a1 = *(const bf16x8*)(arow + (ch * 4 + 1) * 32);
                bf16x8 a2 = *(const bf16x8*)(arow + (ch * 4 + 2) * 32);
                bf16x8 a3 = *(const bf16x8*)(arow + (ch * 4 + 3) * 32);
#pragma unroll
                for (int ot = 0; ot < 4; ++ot) {     // a-frag reused across 4 o-tiles
                    acc[mt][ot] = __builtin_amdgcn_mfma_f32_16x16x32_bf16(a0, w2f[ot][ch * 4 + 0].v, acc[mt][ot], 0, 0, 0);
                    acc[mt][ot] = __builtin_amdgcn_mfma_f32_16x16x32_bf16(a1, w2f[ot][ch * 4 + 1].v, acc[mt][ot], 0, 0, 0);
                    acc[mt][ot] = __builtin_amdgcn_mfma_f32_16x16x32_bf16(a2, w2f[ot][ch * 4 + 2].v, acc[mt][ot], 0, 0, 0);
                    acc[mt][ot] = __builtin_amdgcn_mfma_f32_16x16x32_bf16(a3, w2f[ot][ch * 4 + 3].v, acc[mt][ot], 0, 0, 0);
                }
            }
        }

        // max over 32 neighbors: 8 in-lane (mt x 4 regs) + quad groups (xor 16, 32)
        float mv[4];
#pragma unroll
        for (int ot = 0; ot < 4; ++ot) {
            float m = fmaxf(
                fmaxf(fmaxf(acc[0][ot][0], acc[0][ot][1]), fmaxf(acc[0][ot][2], acc[0][ot][3])),
                fmaxf(fmaxf(acc[1][ot][0], acc[1][ot][1]), fmaxf(acc[1][ot][2], acc[1][ot][3])));
            m = fmaxf(m, __shfl_xor(m, 16));
            m = fmaxf(m, __shfl_xor(m, 32));
            mv[ot] = m;   // constant-indexed (unrolled) -> stays in regs
        }
        const float mlo = (quad & 1) ? mv[1] : mv[0];
        const float mhi = (quad & 1) ? mv[3] : mv[2];
        const float mm  = (quad & 2) ? mhi : mlo;    // quad q holds o-tile q
        out[oidx] = fmaxf(v3 + mm, 0.f);

        if (sn >= NSITES) break;
        s = sn; buf ^= 1;
    }
}

extern "C" void kernel_launch(void* const* d_in, const int* in_sizes, int n_in,
                              void* d_out, int out_size, void* d_ws, size_t ws_size,
                              hipStream_t stream) {
    const float* fi = (const float*)d_in[0];
    const float* fj = (const float*)d_in[1];
    const float* w1 = (const float*)d_in[2];
    const float* b1 = (const float*)d_in[3];
    const float* w2 = (const float*)d_in[4];
    const float* b2 = (const float*)d_in[5];
    float* out = (float*)d_out;

    // V3 staging buffer: workspace if available (lets edge do pure stores to out),
    // else fall back to out (read-before-write per element, as before).
    float* v3buf = (ws_size >= (size_t)NSITES * DIM * sizeof(float)) ? (float*)d_ws : out;

    v3_kernel<<<(NSITES + 63) / 64, 256, 0, stream>>>(fi, w1, b1, w2, b2, v3buf);
    edge_kernel<<<512, 256, 0, stream>>>(fj, w2, v3buf, out);
}